// Round 3
// baseline (127.454 us; speedup 1.0000x reference)
//
#include <hip/hip_runtime.h>
#include <math.h>

#define B_      32
#define NP1     2001
#define D_      512
#define R_      6
#define NROLES  190
#define NVERBS  504
#define VOCAB   2001
#define NREG    2000

#define NSPLIT  32          // n-splits per b -> 1024 blocks for K1
#define CHUNK   64          // rows per block (last split: 16)
#define PSTRIDE 3592        // 6*512 (SW) + 512 (rsum) + 8 (sumexp+pad)
#define WS_SR   0
#define WS_PART 8
#define WS_A    (8 + B_*NSPLIT*PSTRIDE)   // A is 192*512

__device__ __forceinline__ float fast_tanh(float x) {
    // tanh(x) = 1 - 2/(e^{2x}+1);  e^{2x} = 2^{x*2.885390}
    float e = exp2f(x * 2.885390082f);
    return 1.0f - 2.0f * __builtin_amdgcn_rcpf(e + 1.0f);
}
__device__ __forceinline__ float fast_exp(float x) {
    return exp2f(x * 1.442695041f);
}

// Full 64-lane sum, result in all lanes.
// 4 VALU-DPP steps (xor1, xor2 via quad_perm; ror4, ror8 covers row16)
// + ds_swizzle xor16 (within 32) + shfl_xor 32. Only 2 DS ops in the chain.
__device__ __forceinline__ float wave_sum(float v) {
    int x;
    x = __builtin_amdgcn_update_dpp(0, __float_as_int(v), 0xB1, 0xF, 0xF, true);  // quad_perm [1,0,3,2]
    v += __int_as_float(x);
    x = __builtin_amdgcn_update_dpp(0, __float_as_int(v), 0x4E, 0xF, 0xF, true);  // quad_perm [2,3,0,1]
    v += __int_as_float(x);
    x = __builtin_amdgcn_update_dpp(0, __float_as_int(v), 0x124, 0xF, 0xF, true); // row_ror:4
    v += __int_as_float(x);
    x = __builtin_amdgcn_update_dpp(0, __float_as_int(v), 0x128, 0xF, 0xF, true); // row_ror:8
    v += __int_as_float(x);
    x = __builtin_amdgcn_ds_swizzle(__float_as_int(v), 0x401F);                   // xor 16 (within 32)
    v += __int_as_float(x);
    v += __shfl_xor(v, 32, 64);                                                   // cross-half
    return v;
}

// ---------------- K0: s_role[r] + ba  (tiny) ----------------
__global__ __launch_bounds__(1024) void k0_srole(
    const float* __restrict__ roles, const float* __restrict__ Wr,
    const float* __restrict__ br, const float* __restrict__ Wa,
    const float* __restrict__ ba, float* __restrict__ ws_sr) {
    const int tid = threadIdx.x;
    __shared__ float partial[4][NROLES];
    __shared__ float u_s[NROLES];
    const int q = tid >> 8;        // 0..3 -> d-range
    const int k = tid & 255;       // role-emb input index
    if (k < NROLES) {
        float s = 0.f;
        const int d0 = q * 128;
        #pragma unroll 8
        for (int d = 0; d < 128; ++d)
            s += Wr[(size_t)(d0 + d) * NROLES + k] * Wa[d0 + d];
        partial[q][k] = s;
    }
    __syncthreads();
    if (tid < NROLES)
        u_s[tid] = partial[0][tid] + partial[1][tid] + partial[2][tid] + partial[3][tid];
    __syncthreads();
    if (tid < 64) {
        float c0 = 0.f;
        for (int d = tid; d < D_; d += 64) c0 += Wa[d] * br[d];
        #pragma unroll
        for (int m = 1; m < 64; m <<= 1) c0 += __shfl_xor(c0, m, 64);
        for (int r = 0; r < R_; ++r) {
            float p = 0.f;
            for (int kk = tid; kk < NROLES; kk += 64) p += roles[r * NROLES + kk] * u_s[kk];
            #pragma unroll
            for (int m = 1; m < 64; m <<= 1) p += __shfl_xor(p, m, 64);
            if (tid == 0) ws_sr[r] = p + c0 + ba[0];
        }
    }
}

// ---------------- K1: fused main pass over regions ----------------
__global__ __launch_bounds__(256, 4) void k1_main(
    const float* __restrict__ vs, const float* __restrict__ Wa,
    const float* __restrict__ ws_sr, float* __restrict__ part) {
    const int b     = blockIdx.x / NSPLIT;
    const int split = blockIdx.x % NSPLIT;
    const int tid   = threadIdx.x;
    const int lane  = tid & 63;
    const int wave  = tid >> 6;

    // each lane owns 8 contiguous d's: d = lane*8 .. lane*8+7
    const float4 wvA = *reinterpret_cast<const float4*>(Wa + D_ + lane * 8);
    const float4 wvB = *reinterpret_cast<const float4*>(Wa + D_ + lane * 8 + 4);
    float sr[R_];
    #pragma unroll
    for (int r = 0; r < R_; ++r) sr[r] = ws_sr[r];

    float acc[R_][8];
    float rsum[8];
    float sume[R_];
    #pragma unroll
    for (int r = 0; r < R_; ++r) {
        sume[r] = 0.f;
        #pragma unroll
        for (int j = 0; j < 8; ++j) acc[r][j] = 0.f;
    }
    #pragma unroll
    for (int j = 0; j < 8; ++j) rsum[j] = 0.f;

    const float* base = vs + (size_t)b * (NP1 * D_) + D_;   // regions row 0
    const int n0 = split * CHUNK;
    const int n1 = min(n0 + CHUNK, NREG);

    // wave w owns rows n0+2w, n0+2w+1, stepping 8; 2000 % 8 == 0 and
    // n0 % 8 == 0 -> every wave sees whole pairs only.
    int n = n0 + wave * 2;
    bool have = (n + 1 < n1);
    float4 c0A{}, c0B{}, c1A{}, c1B{};
    if (have) {
        const float* r0 = base + (size_t)n * D_ + lane * 8;
        const float* r1 = base + (size_t)(n + 1) * D_ + lane * 8;
        c0A = *reinterpret_cast<const float4*>(r0);
        c0B = *reinterpret_cast<const float4*>(r0 + 4);
        c1A = *reinterpret_cast<const float4*>(r1);
        c1B = *reinterpret_cast<const float4*>(r1 + 4);
    }
    while (have) {
        const int nn = n + 8;
        const bool hn = (nn + 1 < n1);
        float4 p0A{}, p0B{}, p1A{}, p1B{};
        if (hn) {   // issue next pair's loads BEFORE consuming current pair
            const float* r0 = base + (size_t)nn * D_ + lane * 8;
            const float* r1 = base + (size_t)(nn + 1) * D_ + lane * 8;
            p0A = *reinterpret_cast<const float4*>(r0);
            p0B = *reinterpret_cast<const float4*>(r0 + 4);
            p1A = *reinterpret_cast<const float4*>(r1);
            p1B = *reinterpret_cast<const float4*>(r1 + 4);
        }
        float d0 = c0A.x*wvA.x + c0A.y*wvA.y + c0A.z*wvA.z + c0A.w*wvA.w
                 + c0B.x*wvB.x + c0B.y*wvB.y + c0B.z*wvB.z + c0B.w*wvB.w;
        float d1 = c1A.x*wvA.x + c1A.y*wvA.y + c1A.z*wvA.z + c1A.w*wvA.w
                 + c1B.x*wvB.x + c1B.y*wvB.y + c1B.z*wvB.z + c1B.w*wvB.w;
        d0 = wave_sum(d0);
        d1 = wave_sum(d1);
        float xs0[8] = {c0A.x,c0A.y,c0A.z,c0A.w,c0B.x,c0B.y,c0B.z,c0B.w};
        float xs1[8] = {c1A.x,c1A.y,c1A.z,c1A.w,c1B.x,c1B.y,c1B.z,c1B.w};
        #pragma unroll
        for (int r = 0; r < R_; ++r) {
            float t0 = fast_tanh(sr[r] + d0);
            float t1 = fast_tanh(sr[r] + d1);
            sume[r] += fast_exp(t0) + fast_exp(t1);
            #pragma unroll
            for (int j = 0; j < 8; ++j) acc[r][j] += t0 * xs0[j] + t1 * xs1[j];
        }
        #pragma unroll
        for (int j = 0; j < 8; ++j) rsum[j] += xs0[j] + xs1[j];
        c0A = p0A; c0B = p0B; c1A = p1A; c1B = p1B;
        n = nn; have = hn;
    }

    // combine the 4 waves in LDS (deterministic, sequential)
    __shared__ __align__(16) float ls[3584];
    __shared__ float lse_[4][R_];
    for (int w = 0; w < 4; ++w) {
        if (wave == w) {
            #pragma unroll
            for (int j = 0; j < 8; ++j) {
                const int dd = lane * 8 + j;
                if (w == 0) {
                    #pragma unroll
                    for (int r = 0; r < R_; ++r) ls[r * D_ + dd] = acc[r][j];
                    ls[6 * D_ + dd] = rsum[j];
                } else {
                    #pragma unroll
                    for (int r = 0; r < R_; ++r) ls[r * D_ + dd] += acc[r][j];
                    ls[6 * D_ + dd] += rsum[j];
                }
            }
            if (lane == 0) {
                #pragma unroll
                for (int r = 0; r < R_; ++r) lse_[w][r] = sume[r];
            }
        }
        __syncthreads();
    }
    float* dst = part + (size_t)(b * NSPLIT + split) * PSTRIDE;
    for (int i = tid; i < 3584 / 4; i += 256)
        reinterpret_cast<float4*>(dst)[i] = reinterpret_cast<const float4*>(ls)[i];
    if (tid < R_)
        dst[3584 + tid] = lse_[0][tid] + lse_[1][tid] + lse_[2][tid] + lse_[3][tid];
}

// ---------------- K2: reduce partials -> relu(label_embed) ----------------
__global__ __launch_bounds__(256) void k2_reduce(
    const float* __restrict__ part, float* __restrict__ A) {
    const int b = blockIdx.x;
    const int chunk = blockIdx.y;         // 8 chunks of 64 d
    const int t = threadIdx.x;
    const int dl = t & 63;
    const int qg = t >> 6;                // 4 groups of 8 partials
    const int d = chunk * 64 + dl;
    const float* pb = part + (size_t)b * NSPLIT * PSTRIDE;

    float s[7] = {0.f, 0.f, 0.f, 0.f, 0.f, 0.f, 0.f};
    for (int q = qg * 8; q < qg * 8 + 8; ++q) {
        const float* p = pb + (size_t)q * PSTRIDE;
        #pragma unroll
        for (int r = 0; r < R_; ++r) s[r] += p[r * D_ + d];
        s[6] += p[6 * D_ + d];
    }
    __shared__ float red[4][7][64];
    #pragma unroll
    for (int i = 0; i < 7; ++i) red[qg][i][dl] = s[i];
    __shared__ float lse_s[R_];
    if (t < R_) {
        float se = 0.f;
        for (int q = 0; q < NSPLIT; ++q) se += pb[(size_t)q * PSTRIDE + 3584 + t];
        lse_s[t] = logf(se);
    }
    __syncthreads();
    if (t < 64) {
        float rs = red[0][6][dl] + red[1][6][dl] + red[2][6][dl] + red[3][6][dl];
        #pragma unroll
        for (int r = 0; r < R_; ++r) {
            float sw = red[0][r][dl] + red[1][r][dl] + red[2][r][dl] + red[3][r][dl];
            A[((size_t)b * R_ + r) * D_ + d] = fmaxf(sw - lse_s[r] * rs, 0.f);
        }
    }
}

// ---------------- K3: role_label_predict GEMM (192 x 2001 x 512) ----------------
#define BM 32
#define BN 64
#define KC 64
__global__ __launch_bounds__(256) void k3_gemm(
    const float* __restrict__ A, const float* __restrict__ Wl,
    const float* __restrict__ bl, float* __restrict__ out) {
    const int t  = threadIdx.x;
    const int tx = t & 15;           // col group (4 cols)
    const int ty = t >> 4;           // row group (2 rows)
    const int m0 = blockIdx.y * BM;
    const int v0 = blockIdx.x * BN;
    __shared__ __align__(16) float As[KC][34];   // transposed [k][m]
    __shared__ __align__(16) float Bs[KC][68];   // transposed [k][v]
    float acc[2][4] = {{0.f,0.f,0.f,0.f},{0.f,0.f,0.f,0.f}};

    for (int k0 = 0; k0 < D_; k0 += KC) {
        __syncthreads();
        #pragma unroll
        for (int i = 0; i < 2; ++i) {
            int idx = t + i * 256;                // 0..511
            int m = idx >> 4;                     // 0..31
            int kq = (idx & 15) << 2;             // 0..60
            float4 a4 = *reinterpret_cast<const float4*>(A + (size_t)(m0 + m) * D_ + k0 + kq);
            As[kq + 0][m] = a4.x; As[kq + 1][m] = a4.y;
            As[kq + 2][m] = a4.z; As[kq + 3][m] = a4.w;
        }
        #pragma unroll
        for (int i = 0; i < 4; ++i) {
            int idx = t + i * 256;                // 0..1023
            int v = idx >> 4;                     // 0..63
            int kq = (idx & 15) << 2;
            float4 b4 = make_float4(0.f, 0.f, 0.f, 0.f);
            if (v0 + v < VOCAB)
                b4 = *reinterpret_cast<const float4*>(Wl + (size_t)(v0 + v) * D_ + k0 + kq);
            Bs[kq + 0][v] = b4.x; Bs[kq + 1][v] = b4.y;
            Bs[kq + 2][v] = b4.z; Bs[kq + 3][v] = b4.w;
        }
        __syncthreads();
        #pragma unroll 8
        for (int k = 0; k < KC; ++k) {
            float2 a2 = *reinterpret_cast<const float2*>(&As[k][ty * 2]);
            float4 b4 = *reinterpret_cast<const float4*>(&Bs[k][tx * 4]);
            acc[0][0] += a2.x * b4.x; acc[0][1] += a2.x * b4.y;
            acc[0][2] += a2.x * b4.z; acc[0][3] += a2.x * b4.w;
            acc[1][0] += a2.y * b4.x; acc[1][1] += a2.y * b4.y;
            acc[1][2] += a2.y * b4.z; acc[1][3] += a2.y * b4.w;
        }
    }
    #pragma unroll
    for (int i = 0; i < 2; ++i) {
        int m = m0 + ty * 2 + i;
        #pragma unroll
        for (int c = 0; c < 4; ++c) {
            int v = v0 + tx * 4 + c;
            if (v < VOCAB) out[(size_t)m * VOCAB + v] = acc[i][c] + bl[v];
        }
    }
}

// ---------------- K4: verb head ----------------
__global__ __launch_bounds__(256) void k4_verb(
    const float* __restrict__ vs, const float* __restrict__ Wv,
    const float* __restrict__ bv, float* __restrict__ out) {
    const int b = blockIdx.x;
    const int tid = threadIdx.x;
    __shared__ __align__(16) float a_s[D_];
    #pragma unroll
    for (int i = 0; i < 2; ++i) {
        int d = tid + i * 256;
        a_s[d] = fmaxf(vs[(size_t)b * (NP1 * D_) + d], 0.f);
    }
    __syncthreads();
    for (int v = tid; v < NVERBS; v += 256) {
        const float* wrow = Wv + (size_t)v * D_;
        float s = 0.f;
        #pragma unroll 4
        for (int k = 0; k < D_; k += 4) {
            float4 w4 = *reinterpret_cast<const float4*>(wrow + k);
            s += a_s[k] * w4.x + a_s[k + 1] * w4.y + a_s[k + 2] * w4.z + a_s[k + 3] * w4.w;
        }
        out[b * NVERBS + v] = s + bv[v];
    }
}

extern "C" void kernel_launch(void* const* d_in, const int* in_sizes, int n_in,
                              void* d_out, int out_size, void* d_ws, size_t ws_size,
                              hipStream_t stream) {
    const float* vs    = (const float*)d_in[0];
    const float* roles = (const float*)d_in[1];
    const float* Wr    = (const float*)d_in[2];
    const float* br    = (const float*)d_in[3];
    const float* Wa    = (const float*)d_in[4];
    const float* ba    = (const float*)d_in[5];
    const float* Wv    = (const float*)d_in[6];
    const float* bv    = (const float*)d_in[7];
    const float* Wl    = (const float*)d_in[8];
    const float* bl    = (const float*)d_in[9];

    float* out_verb = (float*)d_out;                    // [32][504]
    float* out_role = (float*)d_out + B_ * NVERBS;      // [32][6][2001]
    float* ws       = (float*)d_ws;
    float* ws_sr    = ws + WS_SR;
    float* ws_part  = ws + WS_PART;
    float* ws_A     = ws + WS_A;

    k0_srole<<<dim3(1), dim3(1024), 0, stream>>>(roles, Wr, br, Wa, ba, ws_sr);
    k1_main<<<dim3(B_ * NSPLIT), dim3(256), 0, stream>>>(vs, Wa, ws_sr, ws_part);
    k2_reduce<<<dim3(B_, 8), dim3(256), 0, stream>>>(ws_part, ws_A);
    k3_gemm<<<dim3(32, 6), dim3(256), 0, stream>>>(ws_A, Wl, bl, out_role);
    k4_verb<<<dim3(B_), dim3(256), 0, stream>>>(vs, Wv, bv, out_verb);
}

// Round 4
// 86.153 us; speedup vs baseline: 1.4794x; 1.4794x over previous
//
#include <hip/hip_runtime.h>
#include <math.h>

#define B_      32
#define NP1     2001
#define D_      512
#define R_      6
#define NROLES  190
#define NVERBS  504
#define VOCAB   2001
#define NREG    2000

#define NSPLIT  32
#define CHUNK   64
#define PSTRIDE 3592        // 6*512 (SW) + 512 (rsum) + 8 (sumexp+pad)
// workspace layout (floats)
#define WS_SR   0
#define WS_U    8                         // 8*190 partial u
#define WS_PART 1536
#define WS_A    (1536 + B_*NSPLIT*PSTRIDE)        // 192*512
#define WS_P    (WS_A + 192*D_)                   // 2 * 192*2001 partial gemm
#define PSZ     (192*VOCAB)

__device__ __forceinline__ float fast_tanh(float x) {
    float e = exp2f(x * 2.885390082f);
    return 1.0f - 2.0f * __builtin_amdgcn_rcpf(e + 1.0f);
}
__device__ __forceinline__ float fast_exp(float x) {
    return exp2f(x * 1.442695041f);
}

// 64-lane sum, all lanes get result. 4 DPP (VALU) + ds_swizzle + shfl.
__device__ __forceinline__ float wave_sum(float v) {
    int x;
    x = __builtin_amdgcn_update_dpp(0, __float_as_int(v), 0xB1, 0xF, 0xF, true);
    v += __int_as_float(x);
    x = __builtin_amdgcn_update_dpp(0, __float_as_int(v), 0x4E, 0xF, 0xF, true);
    v += __int_as_float(x);
    x = __builtin_amdgcn_update_dpp(0, __float_as_int(v), 0x124, 0xF, 0xF, true);
    v += __int_as_float(x);
    x = __builtin_amdgcn_update_dpp(0, __float_as_int(v), 0x128, 0xF, 0xF, true);
    v += __int_as_float(x);
    x = __builtin_amdgcn_ds_swizzle(__float_as_int(v), 0x401F);
    v += __int_as_float(x);
    v += __shfl_xor(v, 32, 64);
    return v;
}

// ---------------- K0a: partial u[q][k] = sum_{d in q-range} Wr[d][k]*Wa[d] ----------------
__global__ __launch_bounds__(256) void k0a_upart(
    const float* __restrict__ Wr, const float* __restrict__ Wa,
    float* __restrict__ ws_u) {
    const int q = blockIdx.x;          // 8 blocks, 64 d each
    const int k = threadIdx.x;
    if (k >= NROLES) return;
    float s = 0.f;
    const int d0 = q * 64;
    #pragma unroll 8
    for (int d = 0; d < 64; ++d)
        s += Wr[(size_t)(d0 + d) * NROLES + k] * Wa[d0 + d];
    ws_u[q * NROLES + k] = s;
}

// ---------------- K0b: finish s_role ----------------
__global__ __launch_bounds__(256) void k0b_srole(
    const float* __restrict__ roles, const float* __restrict__ br,
    const float* __restrict__ Wa, const float* __restrict__ ba,
    const float* __restrict__ ws_u, float* __restrict__ ws_sr) {
    const int t = threadIdx.x;
    __shared__ float u_s[NROLES];
    if (t < NROLES) {
        float s = 0.f;
        #pragma unroll
        for (int q = 0; q < 8; ++q) s += ws_u[q * NROLES + t];
        u_s[t] = s;
    }
    __syncthreads();
    if (t < 64) {
        float c0 = 0.f;
        for (int d = t; d < D_; d += 64) c0 += Wa[d] * br[d];
        #pragma unroll
        for (int m = 1; m < 64; m <<= 1) c0 += __shfl_xor(c0, m, 64);
        for (int r = 0; r < R_; ++r) {
            float p = 0.f;
            for (int kk = t; kk < NROLES; kk += 64) p += roles[r * NROLES + kk] * u_s[kk];
            #pragma unroll
            for (int m = 1; m < 64; m <<= 1) p += __shfl_xor(p, m, 64);
            if (t == 0) ws_sr[r] = p + c0 + ba[0];
        }
    }
}

// ---------------- K1: fused main pass over regions ----------------
__global__ __launch_bounds__(256) void k1_main(
    const float* __restrict__ vs, const float* __restrict__ Wa,
    const float* __restrict__ ws_sr, float* __restrict__ part) {
    const int b     = blockIdx.x / NSPLIT;
    const int split = blockIdx.x % NSPLIT;
    const int tid   = threadIdx.x;
    const int lane  = tid & 63;
    const int wave  = tid >> 6;

    // dense pattern: lane covers floats lane*4..lane*4+3 and 256+lane*4..+3
    const float4 wvA = *reinterpret_cast<const float4*>(Wa + D_ + lane * 4);
    const float4 wvB = *reinterpret_cast<const float4*>(Wa + D_ + 256 + lane * 4);
    float sr[R_];
    #pragma unroll
    for (int r = 0; r < R_; ++r) sr[r] = ws_sr[r];

    float acc[R_][8];
    float rsum[8];
    float sume[R_];
    #pragma unroll
    for (int r = 0; r < R_; ++r) {
        sume[r] = 0.f;
        #pragma unroll
        for (int j = 0; j < 8; ++j) acc[r][j] = 0.f;
    }
    #pragma unroll
    for (int j = 0; j < 8; ++j) rsum[j] = 0.f;

    const float* base = vs + (size_t)b * (NP1 * D_) + D_;
    const int n0 = split * CHUNK;
    const int n1 = min(n0 + CHUNK, NREG);

    int n = n0 + wave * 2;
    bool have = (n + 1 < n1);
    float4 c0A{}, c0B{}, c1A{}, c1B{};
    if (have) {
        const float* r0 = base + (size_t)n * D_;
        const float* r1 = base + (size_t)(n + 1) * D_;
        c0A = *reinterpret_cast<const float4*>(r0 + lane * 4);
        c0B = *reinterpret_cast<const float4*>(r0 + 256 + lane * 4);
        c1A = *reinterpret_cast<const float4*>(r1 + lane * 4);
        c1B = *reinterpret_cast<const float4*>(r1 + 256 + lane * 4);
    }
    while (have) {
        const int nn = n + 8;
        const bool hn = (nn + 1 < n1);
        float4 p0A{}, p0B{}, p1A{}, p1B{};
        if (hn) {
            const float* r0 = base + (size_t)nn * D_;
            const float* r1 = base + (size_t)(nn + 1) * D_;
            p0A = *reinterpret_cast<const float4*>(r0 + lane * 4);
            p0B = *reinterpret_cast<const float4*>(r0 + 256 + lane * 4);
            p1A = *reinterpret_cast<const float4*>(r1 + lane * 4);
            p1B = *reinterpret_cast<const float4*>(r1 + 256 + lane * 4);
        }
        float d0 = c0A.x*wvA.x + c0A.y*wvA.y + c0A.z*wvA.z + c0A.w*wvA.w
                 + c0B.x*wvB.x + c0B.y*wvB.y + c0B.z*wvB.z + c0B.w*wvB.w;
        float d1 = c1A.x*wvA.x + c1A.y*wvA.y + c1A.z*wvA.z + c1A.w*wvA.w
                 + c1B.x*wvB.x + c1B.y*wvB.y + c1B.z*wvB.z + c1B.w*wvB.w;
        d0 = wave_sum(d0);
        d1 = wave_sum(d1);
        float xs0[8] = {c0A.x,c0A.y,c0A.z,c0A.w,c0B.x,c0B.y,c0B.z,c0B.w};
        float xs1[8] = {c1A.x,c1A.y,c1A.z,c1A.w,c1B.x,c1B.y,c1B.z,c1B.w};
        #pragma unroll
        for (int r = 0; r < R_; ++r) {
            float t0 = fast_tanh(sr[r] + d0);
            float t1 = fast_tanh(sr[r] + d1);
            sume[r] += fast_exp(t0) + fast_exp(t1);
            #pragma unroll
            for (int j = 0; j < 8; ++j) acc[r][j] += t0 * xs0[j] + t1 * xs1[j];
        }
        #pragma unroll
        for (int j = 0; j < 8; ++j) rsum[j] += xs0[j] + xs1[j];
        c0A = p0A; c0B = p0B; c1A = p1A; c1B = p1B;
        n = nn; have = hn;
    }

    __shared__ __align__(16) float ls[3584];
    __shared__ float lse_[4][R_];
    for (int w = 0; w < 4; ++w) {
        if (wave == w) {
            #pragma unroll
            for (int j = 0; j < 8; ++j) {
                const int dd = (j < 4) ? (lane * 4 + j) : (256 + lane * 4 + (j - 4));
                if (w == 0) {
                    #pragma unroll
                    for (int r = 0; r < R_; ++r) ls[r * D_ + dd] = acc[r][j];
                    ls[6 * D_ + dd] = rsum[j];
                } else {
                    #pragma unroll
                    for (int r = 0; r < R_; ++r) ls[r * D_ + dd] += acc[r][j];
                    ls[6 * D_ + dd] += rsum[j];
                }
            }
            if (lane == 0) {
                #pragma unroll
                for (int r = 0; r < R_; ++r) lse_[w][r] = sume[r];
            }
        }
        __syncthreads();
    }
    float* dst = part + (size_t)(b * NSPLIT + split) * PSTRIDE;
    for (int i = tid; i < 3584 / 4; i += 256)
        reinterpret_cast<float4*>(dst)[i] = reinterpret_cast<const float4*>(ls)[i];
    if (tid < R_)
        dst[3584 + tid] = lse_[0][tid] + lse_[1][tid] + lse_[2][tid] + lse_[3][tid];
}

// ---------------- K2: reduce partials -> relu(label_embed) ----------------
__global__ __launch_bounds__(256) void k2_reduce(
    const float* __restrict__ part, float* __restrict__ A) {
    const int b = blockIdx.x;
    const int chunk = blockIdx.y;
    const int t = threadIdx.x;
    const int dl = t & 63;
    const int qg = t >> 6;
    const int d = chunk * 64 + dl;
    const float* pb = part + (size_t)b * NSPLIT * PSTRIDE;

    float s[7] = {0.f, 0.f, 0.f, 0.f, 0.f, 0.f, 0.f};
    for (int q = qg * 8; q < qg * 8 + 8; ++q) {
        const float* p = pb + (size_t)q * PSTRIDE;
        #pragma unroll
        for (int r = 0; r < R_; ++r) s[r] += p[r * D_ + d];
        s[6] += p[6 * D_ + d];
    }
    __shared__ float red[4][7][64];
    #pragma unroll
    for (int i = 0; i < 7; ++i) red[qg][i][dl] = s[i];
    __shared__ float lse_s[R_];
    if (t < R_) {
        float se = 0.f;
        for (int q = 0; q < NSPLIT; ++q) se += pb[(size_t)q * PSTRIDE + 3584 + t];
        lse_s[t] = logf(se);
    }
    __syncthreads();
    if (t < 64) {
        float rs = red[0][6][dl] + red[1][6][dl] + red[2][6][dl] + red[3][6][dl];
        #pragma unroll
        for (int r = 0; r < R_; ++r) {
            float sw = red[0][r][dl] + red[1][r][dl] + red[2][r][dl] + red[3][r][dl];
            A[((size_t)b * R_ + r) * D_ + d] = fmaxf(sw - lse_s[r] * rs, 0.f);
        }
    }
}

// ---------------- K3: gemm partial, 64x64 tile, 4x4/thread, K split 2 ----------------
#define KC 64
__global__ __launch_bounds__(256) void k3_gemm(
    const float* __restrict__ A, const float* __restrict__ Wl,
    float* __restrict__ P) {
    const int t  = threadIdx.x;
    const int tx = t & 15;           // 4 cols
    const int ty = t >> 4;           // 4 rows
    const int v0 = blockIdx.x * 64;
    const int m0 = blockIdx.y * 64;
    const int kz = blockIdx.z * 256;
    __shared__ __align__(16) float As[KC][68];
    __shared__ __align__(16) float Bs[KC][68];
    float acc[4][4];
    #pragma unroll
    for (int i = 0; i < 4; ++i)
        #pragma unroll
        for (int c = 0; c < 4; ++c) acc[i][c] = 0.f;

    for (int cch = 0; cch < 4; ++cch) {
        const int k0 = kz + cch * KC;
        __syncthreads();
        #pragma unroll
        for (int i = 0; i < 4; ++i) {
            int idx = t + i * 256;                // 0..1023
            int m = idx >> 4;                     // 0..63
            int kq = (idx & 15) << 2;
            float4 a4 = *reinterpret_cast<const float4*>(A + (size_t)(m0 + m) * D_ + k0 + kq);
            As[kq + 0][m] = a4.x; As[kq + 1][m] = a4.y;
            As[kq + 2][m] = a4.z; As[kq + 3][m] = a4.w;
            float4 b4 = make_float4(0.f, 0.f, 0.f, 0.f);
            if (v0 + m < VOCAB)
                b4 = *reinterpret_cast<const float4*>(Wl + (size_t)(v0 + m) * D_ + k0 + kq);
            Bs[kq + 0][m] = b4.x; Bs[kq + 1][m] = b4.y;
            Bs[kq + 2][m] = b4.z; Bs[kq + 3][m] = b4.w;
        }
        __syncthreads();
        #pragma unroll 8
        for (int k = 0; k < KC; ++k) {
            float4 a4 = *reinterpret_cast<const float4*>(&As[k][ty * 4]);
            float4 b4 = *reinterpret_cast<const float4*>(&Bs[k][tx * 4]);
            float av[4] = {a4.x, a4.y, a4.z, a4.w};
            float bv[4] = {b4.x, b4.y, b4.z, b4.w};
            #pragma unroll
            for (int i = 0; i < 4; ++i)
                #pragma unroll
                for (int c = 0; c < 4; ++c) acc[i][c] += av[i] * bv[c];
        }
    }
    float* Pz = P + (size_t)blockIdx.z * PSZ;
    #pragma unroll
    for (int i = 0; i < 4; ++i) {
        int m = m0 + ty * 4 + i;
        #pragma unroll
        for (int c = 0; c < 4; ++c) {
            int v = v0 + tx * 4 + c;
            if (v < VOCAB) Pz[(size_t)m * VOCAB + v] = acc[i][c];
        }
    }
}

// ---------------- K3b: combine halves + bias ----------------
__global__ __launch_bounds__(256) void k3b_add(
    const float* __restrict__ P, const float* __restrict__ bl,
    float* __restrict__ out) {
    const int idx = blockIdx.x * 256 + threadIdx.x;
    if (idx >= PSZ) return;
    const unsigned v = (unsigned)idx % VOCAB;
    out[idx] = P[idx] + P[PSZ + idx] + bl[v];
}

// ---------------- K4: verb head, 128 blocks ----------------
__global__ __launch_bounds__(128) void k4_verb(
    const float* __restrict__ vs, const float* __restrict__ Wv,
    const float* __restrict__ bv, float* __restrict__ out) {
    const int b = blockIdx.x;
    const int g = blockIdx.y;          // verb quarter (126 verbs)
    const int tid = threadIdx.x;
    __shared__ __align__(16) float a_s[D_];
    #pragma unroll
    for (int i = 0; i < 4; ++i) {
        int d = (tid + i * 128) * 1;
        // 512 floats via float4: 128 threads * 4 floats/iter
        if (i == 0) {
            float4 x = reinterpret_cast<const float4*>(vs + (size_t)b * (NP1 * D_))[tid];
            reinterpret_cast<float4*>(a_s)[tid] =
                make_float4(fmaxf(x.x, 0.f), fmaxf(x.y, 0.f), fmaxf(x.z, 0.f), fmaxf(x.w, 0.f));
        }
        (void)d;
    }
    __syncthreads();
    const int v = g * 126 + tid;
    if (tid < 126 && v < NVERBS) {
        const float* wrow = Wv + (size_t)v * D_;
        float s = 0.f;
        #pragma unroll 4
        for (int k = 0; k < D_; k += 4) {
            float4 w4 = *reinterpret_cast<const float4*>(wrow + k);
            s += a_s[k] * w4.x + a_s[k + 1] * w4.y + a_s[k + 2] * w4.z + a_s[k + 3] * w4.w;
        }
        out[b * NVERBS + v] = s + bv[v];
    }
}

extern "C" void kernel_launch(void* const* d_in, const int* in_sizes, int n_in,
                              void* d_out, int out_size, void* d_ws, size_t ws_size,
                              hipStream_t stream) {
    const float* vs    = (const float*)d_in[0];
    const float* roles = (const float*)d_in[1];
    const float* Wr    = (const float*)d_in[2];
    const float* br    = (const float*)d_in[3];
    const float* Wa    = (const float*)d_in[4];
    const float* ba    = (const float*)d_in[5];
    const float* Wv    = (const float*)d_in[6];
    const float* bv    = (const float*)d_in[7];
    const float* Wl    = (const float*)d_in[8];
    const float* bl    = (const float*)d_in[9];

    float* out_verb = (float*)d_out;
    float* out_role = (float*)d_out + B_ * NVERBS;
    float* ws       = (float*)d_ws;

    k0a_upart<<<dim3(8), dim3(256), 0, stream>>>(Wr, Wa, ws + WS_U);
    k0b_srole<<<dim3(1), dim3(256), 0, stream>>>(roles, br, Wa, ba, ws + WS_U, ws + WS_SR);
    k1_main<<<dim3(B_ * NSPLIT), dim3(256), 0, stream>>>(vs, Wa, ws + WS_SR, ws + WS_PART);
    k2_reduce<<<dim3(B_, 8), dim3(256), 0, stream>>>(ws + WS_PART, ws + WS_A);
    k3_gemm<<<dim3(32, 3, 2), dim3(256), 0, stream>>>(ws + WS_A, Wl, ws + WS_P);
    k3b_add<<<dim3((PSZ + 255) / 256), dim3(256), 0, stream>>>(ws + WS_P, bl, out_role);
    k4_verb<<<dim3(B_, 4), dim3(128), 0, stream>>>(vs, Wv, bv, out_verb);
}

// Round 5
// 84.193 us; speedup vs baseline: 1.5138x; 1.0233x over previous
//
#include <hip/hip_runtime.h>
#include <math.h>

#define B_      32
#define NP1     2001
#define D_      512
#define R_      6
#define NROLES  190
#define NVERBS  504
#define VOCAB   2001
#define NREG    2000

#define NSPLIT  32
#define CHUNK   64
#define PSTRIDE 3592        // 6*512 (SW) + 512 (rsum) + 8 (sumexp+pad)
// workspace layout (floats)
#define WS_SR   0
#define WS_U    8
#define WS_PART 1536
#define WS_A    (1536 + B_*NSPLIT*PSTRIDE)
#define WS_P    (WS_A + 192*D_)
#define PSZ     (192*VOCAB)

__device__ __forceinline__ float fast_tanh(float x) {
    float e = exp2f(x * 2.885390082f);
    return 1.0f - 2.0f * __builtin_amdgcn_rcpf(e + 1.0f);
}
__device__ __forceinline__ float fast_exp(float x) {
    return exp2f(x * 1.442695041f);
}

// 64-lane sum, all lanes get result. 4 DPP (VALU) + ds_swizzle + shfl.
__device__ __forceinline__ float wave_sum(float v) {
    int x;
    x = __builtin_amdgcn_update_dpp(0, __float_as_int(v), 0xB1, 0xF, 0xF, true);
    v += __int_as_float(x);
    x = __builtin_amdgcn_update_dpp(0, __float_as_int(v), 0x4E, 0xF, 0xF, true);
    v += __int_as_float(x);
    x = __builtin_amdgcn_update_dpp(0, __float_as_int(v), 0x124, 0xF, 0xF, true);
    v += __int_as_float(x);
    x = __builtin_amdgcn_update_dpp(0, __float_as_int(v), 0x128, 0xF, 0xF, true);
    v += __int_as_float(x);
    x = __builtin_amdgcn_ds_swizzle(__float_as_int(v), 0x401F);
    v += __int_as_float(x);
    v += __shfl_xor(v, 32, 64);
    return v;
}

// async global->LDS, 16 bytes per lane; LDS dest = l + lane*16 (HW), gsrc per-lane
__device__ __forceinline__ void gload_lds16(const float* g, float* l) {
    __builtin_amdgcn_global_load_lds(
        (const __attribute__((address_space(1))) void*)g,
        (__attribute__((address_space(3))) void*)l, 16, 0, 0);
}

// ---------------- K0a: partial u[q][k] ----------------
__global__ __launch_bounds__(256) void k0a_upart(
    const float* __restrict__ Wr, const float* __restrict__ Wa,
    float* __restrict__ ws_u) {
    const int q = blockIdx.x;
    const int k = threadIdx.x;
    if (k >= NROLES) return;
    float s = 0.f;
    const int d0 = q * 64;
    #pragma unroll 8
    for (int d = 0; d < 64; ++d)
        s += Wr[(size_t)(d0 + d) * NROLES + k] * Wa[d0 + d];
    ws_u[q * NROLES + k] = s;
}

// ---------------- K0b: finish s_role ----------------
__global__ __launch_bounds__(256) void k0b_srole(
    const float* __restrict__ roles, const float* __restrict__ br,
    const float* __restrict__ Wa, const float* __restrict__ ba,
    const float* __restrict__ ws_u, float* __restrict__ ws_sr) {
    const int t = threadIdx.x;
    __shared__ float u_s[NROLES];
    if (t < NROLES) {
        float s = 0.f;
        #pragma unroll
        for (int q = 0; q < 8; ++q) s += ws_u[q * NROLES + t];
        u_s[t] = s;
    }
    __syncthreads();
    if (t < 64) {
        float c0 = 0.f;
        for (int d = t; d < D_; d += 64) c0 += Wa[d] * br[d];
        #pragma unroll
        for (int m = 1; m < 64; m <<= 1) c0 += __shfl_xor(c0, m, 64);
        for (int r = 0; r < R_; ++r) {
            float p = 0.f;
            for (int kk = t; kk < NROLES; kk += 64) p += roles[r * NROLES + kk] * u_s[kk];
            #pragma unroll
            for (int m = 1; m < 64; m <<= 1) p += __shfl_xor(p, m, 64);
            if (t == 0) ws_sr[r] = p + c0 + ba[0];
        }
    }
}

// ---------------- K1: fused main pass, async-LDS-ring staged ----------------
// Per wave: 6-row LDS ring (12 KB), global_load_lds 16B, counted vmcnt(4),
// consume 2 rows/iter via ds_read_b128. Wave w owns rows w, w+4, w+8, ...
__global__ __launch_bounds__(256, 4) void k1_main(
    const float* __restrict__ vs, const float* __restrict__ Wa,
    const float* __restrict__ ws_sr, float* __restrict__ part) {
    const int b     = blockIdx.x / NSPLIT;
    const int split = blockIdx.x % NSPLIT;
    const int tid   = threadIdx.x;
    const int lane  = tid & 63;
    const int w     = tid >> 6;

    __shared__ __align__(16) float smem[4 * 6 * 512];   // 48 KB: rings, reused for merge
    __shared__ float lse_[4][R_];
    float* ring = smem + w * (6 * 512);

    const float4 wvA = *reinterpret_cast<const float4*>(Wa + D_ + lane * 4);
    const float4 wvB = *reinterpret_cast<const float4*>(Wa + D_ + 256 + lane * 4);
    float sr[R_];
    #pragma unroll
    for (int r = 0; r < R_; ++r) sr[r] = ws_sr[r];

    float acc[R_][8];
    float rsum[8];
    float sume[R_];
    #pragma unroll
    for (int r = 0; r < R_; ++r) {
        sume[r] = 0.f;
        #pragma unroll
        for (int j = 0; j < 8; ++j) acc[r][j] = 0.f;
    }
    #pragma unroll
    for (int j = 0; j < 8; ++j) rsum[j] = 0.f;

    const float* base = vs + (size_t)b * (NP1 * D_) + D_;
    const int n0 = split * CHUNK;
    const int nrows = min(n0 + CHUNK, NREG) - n0;    // 64 or 16
    const int cnt = (nrows - w + 3) >> 2;            // rows this wave: 16 or 4 (even)
    const int npairs = cnt >> 1;

    // prologue: stage rows 0..3 into slots 0..3 (cnt >= 4 always)
    #pragma unroll
    for (int k = 0; k < 4; ++k) {
        const float* g = base + (size_t)(n0 + w + 4 * k) * D_ + lane * 4;
        float* l = ring + k * 512;
        gload_lds16(g, l);
        gload_lds16(g + 256, l + 256);
    }
    int st_row = 4, st_slot = 4, rd_slot = 0;
    for (int p = 0; p < npairs; ++p) {
        if (p == npairs - 1) {
            asm volatile("s_waitcnt vmcnt(0)" ::: "memory");
        } else {
            asm volatile("s_waitcnt vmcnt(4)" ::: "memory");
        }
        const float* l0 = ring + rd_slot * 512;          // rows 2p, 2p+1 (slots rd, rd+1; rd even)
        float4 x0A = *reinterpret_cast<const float4*>(l0 + lane * 4);
        float4 x0B = *reinterpret_cast<const float4*>(l0 + 256 + lane * 4);
        float4 x1A = *reinterpret_cast<const float4*>(l0 + 512 + lane * 4);
        float4 x1B = *reinterpret_cast<const float4*>(l0 + 768 + lane * 4);
        if (st_row < cnt) {   // stage next pair (slots at ring-distance 4: no hazard)
            const float* g0 = base + (size_t)(n0 + w + 4 * st_row) * D_ + lane * 4;
            float* s0 = ring + st_slot * 512;
            gload_lds16(g0, s0);
            gload_lds16(g0 + 256, s0 + 256);
            const float* g1 = base + (size_t)(n0 + w + 4 * (st_row + 1)) * D_ + lane * 4;
            gload_lds16(g1, s0 + 512);
            gload_lds16(g1 + 256, s0 + 768);
            st_row += 2;
            st_slot += 2; if (st_slot >= 6) st_slot -= 6;
        }
        rd_slot += 2; if (rd_slot >= 6) rd_slot -= 6;

        float d0 = x0A.x*wvA.x + x0A.y*wvA.y + x0A.z*wvA.z + x0A.w*wvA.w
                 + x0B.x*wvB.x + x0B.y*wvB.y + x0B.z*wvB.z + x0B.w*wvB.w;
        float d1 = x1A.x*wvA.x + x1A.y*wvA.y + x1A.z*wvA.z + x1A.w*wvA.w
                 + x1B.x*wvB.x + x1B.y*wvB.y + x1B.z*wvB.z + x1B.w*wvB.w;
        d0 = wave_sum(d0);
        d1 = wave_sum(d1);
        float xs0[8] = {x0A.x,x0A.y,x0A.z,x0A.w,x0B.x,x0B.y,x0B.z,x0B.w};
        float xs1[8] = {x1A.x,x1A.y,x1A.z,x1A.w,x1B.x,x1B.y,x1B.z,x1B.w};
        #pragma unroll
        for (int r = 0; r < R_; ++r) {
            float t0 = fast_tanh(sr[r] + d0);
            float t1 = fast_tanh(sr[r] + d1);
            sume[r] += fast_exp(t0) + fast_exp(t1);
            #pragma unroll
            for (int j = 0; j < 8; ++j) acc[r][j] += t0 * xs0[j] + t1 * xs1[j];
        }
        #pragma unroll
        for (int j = 0; j < 8; ++j) rsum[j] += xs0[j] + xs1[j];
    }

    // merge the 4 waves into smem[0..3583] (smem reused -> barrier first)
    __syncthreads();
    float* ls = smem;
    for (int ww = 0; ww < 4; ++ww) {
        if (w == ww) {
            #pragma unroll
            for (int j = 0; j < 8; ++j) {
                const int dd = (j < 4) ? (lane * 4 + j) : (256 + lane * 4 + (j - 4));
                if (ww == 0) {
                    #pragma unroll
                    for (int r = 0; r < R_; ++r) ls[r * D_ + dd] = acc[r][j];
                    ls[6 * D_ + dd] = rsum[j];
                } else {
                    #pragma unroll
                    for (int r = 0; r < R_; ++r) ls[r * D_ + dd] += acc[r][j];
                    ls[6 * D_ + dd] += rsum[j];
                }
            }
            if (lane == 0) {
                #pragma unroll
                for (int r = 0; r < R_; ++r) lse_[ww][r] = sume[r];
            }
        }
        __syncthreads();
    }
    float* dst = part + (size_t)(b * NSPLIT + split) * PSTRIDE;
    for (int i = tid; i < 3584 / 4; i += 256)
        reinterpret_cast<float4*>(dst)[i] = reinterpret_cast<const float4*>(ls)[i];
    if (tid < R_)
        dst[3584 + tid] = lse_[0][tid] + lse_[1][tid] + lse_[2][tid] + lse_[3][tid];
}

// ---------------- K2: reduce partials -> relu(label_embed) ----------------
__global__ __launch_bounds__(256) void k2_reduce(
    const float* __restrict__ part, float* __restrict__ A) {
    const int b = blockIdx.x;
    const int chunk = blockIdx.y;
    const int t = threadIdx.x;
    const int dl = t & 63;
    const int qg = t >> 6;
    const int d = chunk * 64 + dl;
    const float* pb = part + (size_t)b * NSPLIT * PSTRIDE;

    float s[7] = {0.f, 0.f, 0.f, 0.f, 0.f, 0.f, 0.f};
    for (int q = qg * 8; q < qg * 8 + 8; ++q) {
        const float* p = pb + (size_t)q * PSTRIDE;
        #pragma unroll
        for (int r = 0; r < R_; ++r) s[r] += p[r * D_ + d];
        s[6] += p[6 * D_ + d];
    }
    __shared__ float red[4][7][64];
    #pragma unroll
    for (int i = 0; i < 7; ++i) red[qg][i][dl] = s[i];
    __shared__ float lse_s[R_];
    if (t < R_) {
        float se = 0.f;
        for (int q = 0; q < NSPLIT; ++q) se += pb[(size_t)q * PSTRIDE + 3584 + t];
        lse_s[t] = logf(se);
    }
    __syncthreads();
    if (t < 64) {
        float rs = red[0][6][dl] + red[1][6][dl] + red[2][6][dl] + red[3][6][dl];
        #pragma unroll
        for (int r = 0; r < R_; ++r) {
            float sw = red[0][r][dl] + red[1][r][dl] + red[2][r][dl] + red[3][r][dl];
            A[((size_t)b * R_ + r) * D_ + d] = fmaxf(sw - lse_s[r] * rs, 0.f);
        }
    }
}

// ---------------- K3: gemm partial, 64x64 tile, 4x4/thread, K split 2 ----------------
#define KC 64
__global__ __launch_bounds__(256) void k3_gemm(
    const float* __restrict__ A, const float* __restrict__ Wl,
    float* __restrict__ P) {
    const int t  = threadIdx.x;
    const int tx = t & 15;
    const int ty = t >> 4;
    const int v0 = blockIdx.x * 64;
    const int m0 = blockIdx.y * 64;
    const int kz = blockIdx.z * 256;
    __shared__ __align__(16) float As[KC][68];
    __shared__ __align__(16) float Bs[KC][68];
    float acc[4][4];
    #pragma unroll
    for (int i = 0; i < 4; ++i)
        #pragma unroll
        for (int c = 0; c < 4; ++c) acc[i][c] = 0.f;

    for (int cch = 0; cch < 4; ++cch) {
        const int k0 = kz + cch * KC;
        __syncthreads();
        #pragma unroll
        for (int i = 0; i < 4; ++i) {
            int idx = t + i * 256;
            int m = idx >> 4;
            int kq = (idx & 15) << 2;
            float4 a4 = *reinterpret_cast<const float4*>(A + (size_t)(m0 + m) * D_ + k0 + kq);
            As[kq + 0][m] = a4.x; As[kq + 1][m] = a4.y;
            As[kq + 2][m] = a4.z; As[kq + 3][m] = a4.w;
            float4 b4 = make_float4(0.f, 0.f, 0.f, 0.f);
            if (v0 + m < VOCAB)
                b4 = *reinterpret_cast<const float4*>(Wl + (size_t)(v0 + m) * D_ + k0 + kq);
            Bs[kq + 0][m] = b4.x; Bs[kq + 1][m] = b4.y;
            Bs[kq + 2][m] = b4.z; Bs[kq + 3][m] = b4.w;
        }
        __syncthreads();
        #pragma unroll 8
        for (int k = 0; k < KC; ++k) {
            float4 a4 = *reinterpret_cast<const float4*>(&As[k][ty * 4]);
            float4 b4 = *reinterpret_cast<const float4*>(&Bs[k][tx * 4]);
            float av[4] = {a4.x, a4.y, a4.z, a4.w};
            float bv[4] = {b4.x, b4.y, b4.z, b4.w};
            #pragma unroll
            for (int i = 0; i < 4; ++i)
                #pragma unroll
                for (int c = 0; c < 4; ++c) acc[i][c] += av[i] * bv[c];
        }
    }
    float* Pz = P + (size_t)blockIdx.z * PSZ;
    #pragma unroll
    for (int i = 0; i < 4; ++i) {
        int m = m0 + ty * 4 + i;
        #pragma unroll
        for (int c = 0; c < 4; ++c) {
            int v = v0 + tx * 4 + c;
            if (v < VOCAB) Pz[(size_t)m * VOCAB + v] = acc[i][c];
        }
    }
}

// ---------------- K3b: combine halves + bias ----------------
__global__ __launch_bounds__(256) void k3b_add(
    const float* __restrict__ P, const float* __restrict__ bl,
    float* __restrict__ out) {
    const int idx = blockIdx.x * 256 + threadIdx.x;
    if (idx >= PSZ) return;
    const unsigned v = (unsigned)idx % VOCAB;
    out[idx] = P[idx] + P[PSZ + idx] + bl[v];
}

// ---------------- K4: verb head ----------------
__global__ __launch_bounds__(128) void k4_verb(
    const float* __restrict__ vs, const float* __restrict__ Wv,
    const float* __restrict__ bv, float* __restrict__ out) {
    const int b = blockIdx.x;
    const int g = blockIdx.y;
    const int tid = threadIdx.x;
    __shared__ __align__(16) float a_s[D_];
    float4 x = reinterpret_cast<const float4*>(vs + (size_t)b * (NP1 * D_))[tid];
    reinterpret_cast<float4*>(a_s)[tid] =
        make_float4(fmaxf(x.x, 0.f), fmaxf(x.y, 0.f), fmaxf(x.z, 0.f), fmaxf(x.w, 0.f));
    __syncthreads();
    const int v = g * 126 + tid;
    if (tid < 126 && v < NVERBS) {
        const float* wrow = Wv + (size_t)v * D_;
        float s = 0.f;
        #pragma unroll 4
        for (int k = 0; k < D_; k += 4) {
            float4 w4 = *reinterpret_cast<const float4*>(wrow + k);
            s += a_s[k] * w4.x + a_s[k + 1] * w4.y + a_s[k + 2] * w4.z + a_s[k + 3] * w4.w;
        }
        out[b * NVERBS + v] = s + bv[v];
    }
}

extern "C" void kernel_launch(void* const* d_in, const int* in_sizes, int n_in,
                              void* d_out, int out_size, void* d_ws, size_t ws_size,
                              hipStream_t stream) {
    const float* vs    = (const float*)d_in[0];
    const float* roles = (const float*)d_in[1];
    const float* Wr    = (const float*)d_in[2];
    const float* br    = (const float*)d_in[3];
    const float* Wa    = (const float*)d_in[4];
    const float* ba    = (const float*)d_in[5];
    const float* Wv    = (const float*)d_in[6];
    const float* bv    = (const float*)d_in[7];
    const float* Wl    = (const float*)d_in[8];
    const float* bl    = (const float*)d_in[9];

    float* out_verb = (float*)d_out;
    float* out_role = (float*)d_out + B_ * NVERBS;
    float* ws       = (float*)d_ws;

    k0a_upart<<<dim3(8), dim3(256), 0, stream>>>(Wr, Wa, ws + WS_U);
    k0b_srole<<<dim3(1), dim3(256), 0, stream>>>(roles, br, Wa, ba, ws + WS_U, ws + WS_SR);
    k1_main<<<dim3(B_ * NSPLIT), dim3(256), 0, stream>>>(vs, Wa, ws + WS_SR, ws + WS_PART);
    k2_reduce<<<dim3(B_, 8), dim3(256), 0, stream>>>(ws + WS_PART, ws + WS_A);
    k3_gemm<<<dim3(32, 3, 2), dim3(256), 0, stream>>>(ws + WS_A, Wl, ws + WS_P);
    k3b_add<<<dim3((PSZ + 255) / 256), dim3(256), 0, stream>>>(ws + WS_P, bl, out_role);
    k4_verb<<<dim3(B_, 4), dim3(128), 0, stream>>>(vs, Wv, bv, out_verb);
}

// Round 6
// 82.467 us; speedup vs baseline: 1.5455x; 1.0209x over previous
//
#include <hip/hip_runtime.h>
#include <math.h>

#define B_      32
#define NP1     2001
#define D_      512
#define R_      6
#define NROLES  190
#define NVERBS  504
#define VOCAB   2001
#define NREG    2000

#define NSPLIT  32
#define CHUNK   64
#define PSTRIDE 3592        // 6*512 (SW) + 512 (rsum) + 8 (sumexp+pad)
// workspace layout (floats)
#define WS_U    8
#define WS_PART 1536
#define WS_A    (1536 + B_*NSPLIT*PSTRIDE)
#define WS_P    (WS_A + 192*D_)
#define PSZ     (192*VOCAB)
#define NB3B    1501        // ceil(PSZ/256)

__device__ __forceinline__ float fast_tanh(float x) {
    float e = exp2f(x * 2.885390082f);
    return 1.0f - 2.0f * __builtin_amdgcn_rcpf(e + 1.0f);
}
__device__ __forceinline__ float fast_exp(float x) {
    return exp2f(x * 1.442695041f);
}

// 64-lane sum, all lanes get result. 4 DPP (VALU) + ds_swizzle + shfl.
__device__ __forceinline__ float wave_sum(float v) {
    int x;
    x = __builtin_amdgcn_update_dpp(0, __float_as_int(v), 0xB1, 0xF, 0xF, true);
    v += __int_as_float(x);
    x = __builtin_amdgcn_update_dpp(0, __float_as_int(v), 0x4E, 0xF, 0xF, true);
    v += __int_as_float(x);
    x = __builtin_amdgcn_update_dpp(0, __float_as_int(v), 0x124, 0xF, 0xF, true);
    v += __int_as_float(x);
    x = __builtin_amdgcn_update_dpp(0, __float_as_int(v), 0x128, 0xF, 0xF, true);
    v += __int_as_float(x);
    x = __builtin_amdgcn_ds_swizzle(__float_as_int(v), 0x401F);
    v += __int_as_float(x);
    v += __shfl_xor(v, 32, 64);
    return v;
}

// async global->LDS, 16B/lane; LDS dest = l + lane*16 (HW adds lane offset)
__device__ __forceinline__ void gload_lds16(const float* g, float* l) {
    __builtin_amdgcn_global_load_lds(
        (const __attribute__((address_space(1))) void*)g,
        (__attribute__((address_space(3))) void*)l, 16, 0, 0);
}

// ---------------- K0a: partial u[q][k] = sum_{d in q*64..} Wr[d][k]*Wa[d] ----------------
__global__ __launch_bounds__(256) void k0a_upart(
    const float* __restrict__ Wr, const float* __restrict__ Wa,
    float* __restrict__ ws_u) {
    const int q = blockIdx.x;
    const int k = threadIdx.x;
    if (k >= NROLES) return;
    float s = 0.f;
    const int d0 = q * 64;
    #pragma unroll 8
    for (int d = 0; d < 64; ++d)
        s += Wr[(size_t)(d0 + d) * NROLES + k] * Wa[d0 + d];
    ws_u[q * NROLES + k] = s;
}

// ---------------- K1: fused main pass; inline s_role; 3-pair async LDS ring ----------------
__global__ __launch_bounds__(256, 4) void k1_main(
    const float* __restrict__ vs, const float* __restrict__ Wa,
    const float* __restrict__ roles, const float* __restrict__ br,
    const float* __restrict__ ba, const float* __restrict__ ws_u,
    float* __restrict__ part) {
    const int b     = blockIdx.x / NSPLIT;
    const int split = blockIdx.x % NSPLIT;
    const int tid   = threadIdx.x;
    const int lane  = tid & 63;
    const int w     = tid >> 6;

    __shared__ __align__(16) float smem[4 * 3 * 1024];   // 48 KB rings; reused for merge
    __shared__ float lse_[4][R_];
    float* ring = smem + w * 3072;

    const float4 wvA = *reinterpret_cast<const float4*>(Wa + D_ + lane * 4);
    const float4 wvB = *reinterpret_cast<const float4*>(Wa + D_ + 256 + lane * 4);

    // ---- inline s_role (redundant per wave; all L2-resident reads) ----
    float sr[R_];
    {
        float pr[R_] = {0.f, 0.f, 0.f, 0.f, 0.f, 0.f};
        #pragma unroll
        for (int i = 0; i < 3; ++i) {
            const int k = lane + i * 64;
            if (k < NROLES) {
                float u = 0.f;
                #pragma unroll
                for (int q = 0; q < 8; ++q) u += ws_u[q * NROLES + k];
                #pragma unroll
                for (int r = 0; r < R_; ++r) pr[r] += roles[r * NROLES + k] * u;
            }
        }
        float c0 = 0.f;
        #pragma unroll
        for (int i = 0; i < 8; ++i) c0 += Wa[lane + i * 64] * br[lane + i * 64];
        c0 = wave_sum(c0) + ba[0];
        #pragma unroll
        for (int r = 0; r < R_; ++r) sr[r] = wave_sum(pr[r]) + c0;
    }

    float acc[R_][8];
    float rsum[8];
    float sume[R_];
    #pragma unroll
    for (int r = 0; r < R_; ++r) {
        sume[r] = 0.f;
        #pragma unroll
        for (int j = 0; j < 8; ++j) acc[r][j] = 0.f;
    }
    #pragma unroll
    for (int j = 0; j < 8; ++j) rsum[j] = 0.f;

    const float* base = vs + (size_t)b * (NP1 * D_) + D_;
    const int n0 = split * CHUNK;
    const int nrows = min(n0 + CHUNK, NREG) - n0;    // 64 or 16
    const int cnt = (nrows - w + 3) >> 2;            // rows this wave (16 or 4)
    const int npairs = cnt >> 1;                     // 8 or 2

    // fence: all sr loads consumed above; from here only gload_lds is outstanding
    asm volatile("" ::: "memory");

    // prologue: stage up to 3 pairs. pair p = global rows n0+w+8p, n0+w+8p+4; slot p%3
    const int nst = min(3, npairs);
    for (int k = 0; k < nst; ++k) {
        const float* g0 = base + (size_t)(n0 + w + 8 * k) * D_ + lane * 4;
        float* s0 = ring + k * 1024;
        gload_lds16(g0, s0);
        gload_lds16(g0 + 256, s0 + 256);
        const float* g1 = g0 + 4 * D_;
        gload_lds16(g1, s0 + 512);
        gload_lds16(g1 + 256, s0 + 768);
    }
    int st = nst;
    for (int p = 0; p < npairs; ++p) {
        const int rem = npairs - p;       // outstanding pairs = min(3, rem)
        if (rem > 2)       asm volatile("s_waitcnt vmcnt(8)" ::: "memory");
        else if (rem == 2) asm volatile("s_waitcnt vmcnt(4)" ::: "memory");
        else               asm volatile("s_waitcnt vmcnt(0)" ::: "memory");

        const float* l0 = ring + (p % 3) * 1024;
        float4 x0A = *reinterpret_cast<const float4*>(l0 + lane * 4);
        float4 x0B = *reinterpret_cast<const float4*>(l0 + 256 + lane * 4);
        float4 x1A = *reinterpret_cast<const float4*>(l0 + 512 + lane * 4);
        float4 x1B = *reinterpret_cast<const float4*>(l0 + 768 + lane * 4);
        // consume (forces lgkm wait) BEFORE overwriting the slot
        float d0 = x0A.x*wvA.x + x0A.y*wvA.y + x0A.z*wvA.z + x0A.w*wvA.w
                 + x0B.x*wvB.x + x0B.y*wvB.y + x0B.z*wvB.z + x0B.w*wvB.w;
        float d1 = x1A.x*wvA.x + x1A.y*wvA.y + x1A.z*wvA.z + x1A.w*wvA.w
                 + x1B.x*wvB.x + x1B.y*wvB.y + x1B.z*wvB.z + x1B.w*wvB.w;
        if (st < npairs) {                 // refill the slot just consumed
            const float* g0 = base + (size_t)(n0 + w + 8 * st) * D_ + lane * 4;
            float* s0 = ring + (st % 3) * 1024;
            gload_lds16(g0, s0);
            gload_lds16(g0 + 256, s0 + 256);
            const float* g1 = g0 + 4 * D_;
            gload_lds16(g1, s0 + 512);
            gload_lds16(g1 + 256, s0 + 768);
            ++st;
        }
        d0 = wave_sum(d0);
        d1 = wave_sum(d1);
        float xs0[8] = {x0A.x,x0A.y,x0A.z,x0A.w,x0B.x,x0B.y,x0B.z,x0B.w};
        float xs1[8] = {x1A.x,x1A.y,x1A.z,x1A.w,x1B.x,x1B.y,x1B.z,x1B.w};
        #pragma unroll
        for (int r = 0; r < R_; ++r) {
            float t0 = fast_tanh(sr[r] + d0);
            float t1 = fast_tanh(sr[r] + d1);
            sume[r] += fast_exp(t0) + fast_exp(t1);
            #pragma unroll
            for (int j = 0; j < 8; ++j) acc[r][j] += t0 * xs0[j] + t1 * xs1[j];
        }
        #pragma unroll
        for (int j = 0; j < 8; ++j) rsum[j] += xs0[j] + xs1[j];
    }

    // merge the 4 waves into smem[0..3583] (reused -> barrier first)
    __syncthreads();
    float* ls = smem;
    for (int ww = 0; ww < 4; ++ww) {
        if (w == ww) {
            #pragma unroll
            for (int j = 0; j < 8; ++j) {
                const int dd = (j < 4) ? (lane * 4 + j) : (256 + lane * 4 + (j - 4));
                if (ww == 0) {
                    #pragma unroll
                    for (int r = 0; r < R_; ++r) ls[r * D_ + dd] = acc[r][j];
                    ls[6 * D_ + dd] = rsum[j];
                } else {
                    #pragma unroll
                    for (int r = 0; r < R_; ++r) ls[r * D_ + dd] += acc[r][j];
                    ls[6 * D_ + dd] += rsum[j];
                }
            }
            if (lane == 0) {
                #pragma unroll
                for (int r = 0; r < R_; ++r) lse_[ww][r] = sume[r];
            }
        }
        __syncthreads();
    }
    float* dst = part + (size_t)(b * NSPLIT + split) * PSTRIDE;
    for (int i = tid; i < 3584 / 4; i += 256)
        reinterpret_cast<float4*>(dst)[i] = reinterpret_cast<const float4*>(ls)[i];
    if (tid < R_)
        dst[3584 + tid] = lse_[0][tid] + lse_[1][tid] + lse_[2][tid] + lse_[3][tid];
}

// ---------------- K2: reduce partials -> relu(label_embed) ----------------
__global__ __launch_bounds__(256) void k2_reduce(
    const float* __restrict__ part, float* __restrict__ A) {
    const int b = blockIdx.x;
    const int chunk = blockIdx.y;
    const int t = threadIdx.x;
    const int dl = t & 63;
    const int qg = t >> 6;
    const int d = chunk * 64 + dl;
    const float* pb = part + (size_t)b * NSPLIT * PSTRIDE;

    float s[7] = {0.f, 0.f, 0.f, 0.f, 0.f, 0.f, 0.f};
    for (int q = qg * 8; q < qg * 8 + 8; ++q) {
        const float* p = pb + (size_t)q * PSTRIDE;
        #pragma unroll
        for (int r = 0; r < R_; ++r) s[r] += p[r * D_ + d];
        s[6] += p[6 * D_ + d];
    }
    __shared__ float red[4][7][64];
    #pragma unroll
    for (int i = 0; i < 7; ++i) red[qg][i][dl] = s[i];
    __shared__ float lse_s[R_];
    if (t < R_) {
        float se = 0.f;
        for (int q = 0; q < NSPLIT; ++q) se += pb[(size_t)q * PSTRIDE + 3584 + t];
        lse_s[t] = logf(se);
    }
    __syncthreads();
    if (t < 64) {
        float rs = red[0][6][dl] + red[1][6][dl] + red[2][6][dl] + red[3][6][dl];
        #pragma unroll
        for (int r = 0; r < R_; ++r) {
            float sw = red[0][r][dl] + red[1][r][dl] + red[2][r][dl] + red[3][r][dl];
            A[((size_t)b * R_ + r) * D_ + d] = fmaxf(sw - lse_s[r] * rs, 0.f);
        }
    }
}

// ---------------- K3: gemm partial, 64x64 tile, 4x4/thread, K split 2 ----------------
#define KC 64
__global__ __launch_bounds__(256) void k3_gemm(
    const float* __restrict__ A, const float* __restrict__ Wl,
    float* __restrict__ P) {
    const int t  = threadIdx.x;
    const int tx = t & 15;
    const int ty = t >> 4;
    const int v0 = blockIdx.x * 64;
    const int m0 = blockIdx.y * 64;
    const int kz = blockIdx.z * 256;
    __shared__ __align__(16) float As[KC][68];
    __shared__ __align__(16) float Bs[KC][68];
    float acc[4][4];
    #pragma unroll
    for (int i = 0; i < 4; ++i)
        #pragma unroll
        for (int c = 0; c < 4; ++c) acc[i][c] = 0.f;

    for (int cch = 0; cch < 4; ++cch) {
        const int k0 = kz + cch * KC;
        __syncthreads();
        #pragma unroll
        for (int i = 0; i < 4; ++i) {
            int idx = t + i * 256;
            int m = idx >> 4;
            int kq = (idx & 15) << 2;
            float4 a4 = *reinterpret_cast<const float4*>(A + (size_t)(m0 + m) * D_ + k0 + kq);
            As[kq + 0][m] = a4.x; As[kq + 1][m] = a4.y;
            As[kq + 2][m] = a4.z; As[kq + 3][m] = a4.w;
            float4 b4 = make_float4(0.f, 0.f, 0.f, 0.f);
            if (v0 + m < VOCAB)
                b4 = *reinterpret_cast<const float4*>(Wl + (size_t)(v0 + m) * D_ + k0 + kq);
            Bs[kq + 0][m] = b4.x; Bs[kq + 1][m] = b4.y;
            Bs[kq + 2][m] = b4.z; Bs[kq + 3][m] = b4.w;
        }
        __syncthreads();
        #pragma unroll 8
        for (int k = 0; k < KC; ++k) {
            float4 a4 = *reinterpret_cast<const float4*>(&As[k][ty * 4]);
            float4 b4 = *reinterpret_cast<const float4*>(&Bs[k][tx * 4]);
            float av[4] = {a4.x, a4.y, a4.z, a4.w};
            float bv[4] = {b4.x, b4.y, b4.z, b4.w};
            #pragma unroll
            for (int i = 0; i < 4; ++i)
                #pragma unroll
                for (int c = 0; c < 4; ++c) acc[i][c] += av[i] * bv[c];
        }
    }
    float* Pz = P + (size_t)blockIdx.z * PSZ;
    #pragma unroll
    for (int i = 0; i < 4; ++i) {
        int m = m0 + ty * 4 + i;
        #pragma unroll
        for (int c = 0; c < 4; ++c) {
            int v = v0 + tx * 4 + c;
            if (v < VOCAB) Pz[(size_t)m * VOCAB + v] = acc[i][c];
        }
    }
}

// ---------------- K_tail: {combine gemm halves + bias} ∪ {verb head} ----------------
__global__ __launch_bounds__(256) void k_tail(
    const float* __restrict__ P, const float* __restrict__ bl,
    float* __restrict__ out_role,
    const float* __restrict__ vs, const float* __restrict__ Wv,
    const float* __restrict__ bv, float* __restrict__ out_verb) {
    const int bid = blockIdx.x;
    const int tid = threadIdx.x;
    if (bid < NB3B) {
        const int idx = bid * 256 + tid;
        if (idx < PSZ) {
            const unsigned v = (unsigned)idx % VOCAB;
            out_role[idx] = P[idx] + P[PSZ + idx] + bl[v];
        }
    } else {
        const int q = bid - NB3B;       // 0..63
        const int b = q >> 1;
        const int g = q & 1;
        __shared__ __align__(16) float a_s[D_];
        float2 x = reinterpret_cast<const float2*>(vs + (size_t)b * (NP1 * D_))[tid];
        reinterpret_cast<float2*>(a_s)[tid] = make_float2(fmaxf(x.x, 0.f), fmaxf(x.y, 0.f));
        __syncthreads();
        const int v = g * 252 + tid;
        if (tid < 252 && v < NVERBS) {
            const float* wrow = Wv + (size_t)v * D_;
            float s = 0.f;
            #pragma unroll 4
            for (int k = 0; k < D_; k += 4) {
                float4 w4 = *reinterpret_cast<const float4*>(wrow + k);
                s += a_s[k] * w4.x + a_s[k + 1] * w4.y + a_s[k + 2] * w4.z + a_s[k + 3] * w4.w;
            }
            out_verb[b * NVERBS + v] = s + bv[v];
        }
    }
}

extern "C" void kernel_launch(void* const* d_in, const int* in_sizes, int n_in,
                              void* d_out, int out_size, void* d_ws, size_t ws_size,
                              hipStream_t stream) {
    const float* vs    = (const float*)d_in[0];
    const float* roles = (const float*)d_in[1];
    const float* Wr    = (const float*)d_in[2];
    const float* br    = (const float*)d_in[3];
    const float* Wa    = (const float*)d_in[4];
    const float* ba    = (const float*)d_in[5];
    const float* Wv    = (const float*)d_in[6];
    const float* bv    = (const float*)d_in[7];
    const float* Wl    = (const float*)d_in[8];
    const float* bl    = (const float*)d_in[9];

    float* out_verb = (float*)d_out;
    float* out_role = (float*)d_out + B_ * NVERBS;
    float* ws       = (float*)d_ws;

    k0a_upart<<<dim3(8), dim3(256), 0, stream>>>(Wr, Wa, ws + WS_U);
    k1_main<<<dim3(B_ * NSPLIT), dim3(256), 0, stream>>>(vs, Wa, roles, br, ba,
                                                         ws + WS_U, ws + WS_PART);
    k2_reduce<<<dim3(B_, 8), dim3(256), 0, stream>>>(ws + WS_PART, ws + WS_A);
    k3_gemm<<<dim3(32, 3, 2), dim3(256), 0, stream>>>(ws + WS_A, Wl, ws + WS_P);
    k_tail<<<dim3(NB3B + 64), dim3(256), 0, stream>>>(ws + WS_P, bl, out_role,
                                                      vs, Wv, bv, out_verb);
}